// Round 4
// baseline (766.079 us; speedup 1.0000x reference)
//
#include <hip/hip_runtime.h>

typedef int vint4 __attribute__((ext_vector_type(4)));

#define NUM_XCD 8

// ---------------- common geometry ----------------
struct V3 { float x, y, z; };

__device__ __forceinline__ void compute_tet(
    V3 v0, V3 v1, V3 v2, V3 v3, float d, float& area, float& alpha)
{
    float e1x = v1.x - v0.x, e1y = v1.y - v0.y, e1z = v1.z - v0.z;
    float e2x = v2.x - v0.x, e2y = v2.y - v0.y, e2z = v2.z - v0.z;
    float e3x = v3.x - v0.x, e3y = v3.y - v0.y, e3z = v3.z - v0.z;

    float det = e1x * (e2y * e3z - e2z * e3y)
              - e1y * (e2x * e3z - e2z * e3x)
              + e1z * (e2x * e3y - e2y * e3x);
    area = fabsf(det) * (1.0f / 6.0f);

    float q01 = e1x * e1x + e1y * e1y + e1z * e1z;
    float q02 = e2x * e2x + e2y * e2y + e2z * e2z;
    float q03 = e3x * e3x + e3y * e3y + e3z * e3z;
    float ax, ay, az;
    ax = v1.x - v2.x; ay = v1.y - v2.y; az = v1.z - v2.z;
    float q12 = ax * ax + ay * ay + az * az;
    ax = v1.x - v3.x; ay = v1.y - v3.y; az = v1.z - v3.z;
    float q13 = ax * ax + ay * ay + az * az;
    ax = v2.x - v3.x; ay = v2.y - v3.y; az = v2.z - v3.z;
    float q23 = ax * ax + ay * ay + az * az;

    float mn = fminf(fminf(fminf(q01, q02), fminf(q03, q12)), fminf(q13, q23));
    float el = sqrtf(mn);
    alpha = 1.0f - expf(-d * el);
}

// ---------------- fast path ----------------

// Repack verts (V x 3 floats) -> float4 (16B aligned) so each gather is one dwordx4.
__global__ __launch_bounds__(256) void repack_kernel(
    const float* __restrict__ verts, float4* __restrict__ packed, int V)
{
    int v = blockIdx.x * blockDim.x + threadIdx.x;
    if (v >= V) return;
    const float* p = verts + (size_t)v * 3;
    packed[v] = make_float4(p[0], p[1], p[2], 0.f);
}

__device__ __forceinline__ V3 load_vert4(const float4* __restrict__ packed, int idx) {
    float4 f = packed[idx];
    V3 r; r.x = f.x; r.y = f.y; r.z = f.z;
    return r;
}

__global__ __launch_bounds__(256) void tet_kernel_fast(
    const float4* __restrict__ packed,
    const int*    __restrict__ indices,   // flat, 4 per tet
    const float*  __restrict__ density,
    float* __restrict__ out_area,
    float* __restrict__ out_alpha,
    unsigned int* __restrict__ vd_copies, // NUM_XCD copies of V uints
    int T, int V)
{
    int tid = blockIdx.x * blockDim.x + threadIdx.x;
    int H = T >> 1;
    if (tid >= H) return;
    int i0 = tid, i1 = tid + H;

    // which physical XCD are we on? (wave-uniform SGPR read, verified m09)
    unsigned int xcc;
    asm volatile("s_getreg_b32 %0, hwreg(HW_REG_XCC_ID)" : "=s"(xcc));
    unsigned int* __restrict__ vd = vd_copies + (size_t)(xcc & (NUM_XCD - 1)) * V;

    vint4 idxA = __builtin_nontemporal_load((const vint4*)indices + i0);
    vint4 idxB = __builtin_nontemporal_load((const vint4*)indices + i1);
    float dA   = __builtin_nontemporal_load(density + i0);
    float dB   = __builtin_nontemporal_load(density + i1);

    V3 a0 = load_vert4(packed, idxA.x);
    V3 a1 = load_vert4(packed, idxA.y);
    V3 a2 = load_vert4(packed, idxA.z);
    V3 a3 = load_vert4(packed, idxA.w);
    V3 b0 = load_vert4(packed, idxB.x);
    V3 b1 = load_vert4(packed, idxB.y);
    V3 b2 = load_vert4(packed, idxB.z);
    V3 b3 = load_vert4(packed, idxB.w);

    float areaA, alphaA, areaB, alphaB;
    compute_tet(a0, a1, a2, a3, dA, areaA, alphaA);
    compute_tet(b0, b1, b2, b3, dB, areaB, alphaB);

    __builtin_nontemporal_store(areaA,  out_area + i0);
    __builtin_nontemporal_store(areaB,  out_area + i1);
    __builtin_nontemporal_store(alphaA, out_alpha + i0);
    __builtin_nontemporal_store(alphaB, out_alpha + i1);

    // Workgroup-scope atomics execute at the local XCD's L2 (no fabric crossing).
    // Coherent across the XCD since all vector atomics RMW at L2; each XCD has
    // its own private copy so no cross-XCD coherence is needed.
    unsigned int dbA = __float_as_uint(dA);
    unsigned int dbB = __float_as_uint(dB);
    __hip_atomic_fetch_max(vd + idxA.x, dbA, __ATOMIC_RELAXED, __HIP_MEMORY_SCOPE_WORKGROUP);
    __hip_atomic_fetch_max(vd + idxA.y, dbA, __ATOMIC_RELAXED, __HIP_MEMORY_SCOPE_WORKGROUP);
    __hip_atomic_fetch_max(vd + idxA.z, dbA, __ATOMIC_RELAXED, __HIP_MEMORY_SCOPE_WORKGROUP);
    __hip_atomic_fetch_max(vd + idxA.w, dbA, __ATOMIC_RELAXED, __HIP_MEMORY_SCOPE_WORKGROUP);
    __hip_atomic_fetch_max(vd + idxB.x, dbB, __ATOMIC_RELAXED, __HIP_MEMORY_SCOPE_WORKGROUP);
    __hip_atomic_fetch_max(vd + idxB.y, dbB, __ATOMIC_RELAXED, __HIP_MEMORY_SCOPE_WORKGROUP);
    __hip_atomic_fetch_max(vd + idxB.z, dbB, __ATOMIC_RELAXED, __HIP_MEMORY_SCOPE_WORKGROUP);
    __hip_atomic_fetch_max(vd + idxB.w, dbB, __ATOMIC_RELAXED, __HIP_MEMORY_SCOPE_WORKGROUP);
}

// Final: vd_out[v] = max over the 8 per-XCD copies (zero identity already ensures >= 0).
__global__ __launch_bounds__(256) void reduce_vd_kernel(
    const uint4* __restrict__ vd_copies,  // NUM_XCD x (V/4) uint4
    uint4* __restrict__ vd_out, int n4, int V)
{
    int i = blockIdx.x * blockDim.x + threadIdx.x;
    if (i >= n4) return;
    int stride4 = V >> 2;
    uint4 m = vd_copies[i];
    #pragma unroll
    for (int c = 1; c < NUM_XCD; ++c) {
        uint4 t = vd_copies[(size_t)c * stride4 + i];
        m.x = max(m.x, t.x); m.y = max(m.y, t.y);
        m.z = max(m.z, t.z); m.w = max(m.w, t.w);
    }
    vd_out[i] = m;
}

// ---------------- fallback path (round-3 proven) ----------------
__global__ __launch_bounds__(256) void zero_vd_kernel(float4* __restrict__ vd4, int n4) {
    int i = blockIdx.x * blockDim.x + threadIdx.x;
    if (i < n4) vd4[i] = make_float4(0.f, 0.f, 0.f, 0.f);
}

__device__ __forceinline__ V3 load_vert(const float* __restrict__ verts, int idx) {
    const float* p = verts + (size_t)idx * 3;
    V3 r; r.x = p[0]; r.y = p[1]; r.z = p[2];
    return r;
}

__global__ __launch_bounds__(256) void tet_kernel_fb(
    const float* __restrict__ verts,
    const int*   __restrict__ indices,
    const float* __restrict__ density,
    float* __restrict__ out_area,
    float* __restrict__ out_alpha,
    unsigned int* __restrict__ vd,
    int T)
{
    int tid = blockIdx.x * blockDim.x + threadIdx.x;
    int H = T >> 1;
    if (tid >= H) return;
    int i0 = tid, i1 = tid + H;

    vint4 idxA = __builtin_nontemporal_load((const vint4*)indices + i0);
    vint4 idxB = __builtin_nontemporal_load((const vint4*)indices + i1);
    float dA   = __builtin_nontemporal_load(density + i0);
    float dB   = __builtin_nontemporal_load(density + i1);

    V3 a0 = load_vert(verts, idxA.x);
    V3 a1 = load_vert(verts, idxA.y);
    V3 a2 = load_vert(verts, idxA.z);
    V3 a3 = load_vert(verts, idxA.w);
    V3 b0 = load_vert(verts, idxB.x);
    V3 b1 = load_vert(verts, idxB.y);
    V3 b2 = load_vert(verts, idxB.z);
    V3 b3 = load_vert(verts, idxB.w);

    float areaA, alphaA, areaB, alphaB;
    compute_tet(a0, a1, a2, a3, dA, areaA, alphaA);
    compute_tet(b0, b1, b2, b3, dB, areaB, alphaB);

    __builtin_nontemporal_store(areaA,  out_area + i0);
    __builtin_nontemporal_store(areaB,  out_area + i1);
    __builtin_nontemporal_store(alphaA, out_alpha + i0);
    __builtin_nontemporal_store(alphaB, out_alpha + i1);

    unsigned int dbA = __float_as_uint(dA);
    unsigned int dbB = __float_as_uint(dB);
    atomicMax(vd + idxA.x, dbA);
    atomicMax(vd + idxA.y, dbA);
    atomicMax(vd + idxA.z, dbA);
    atomicMax(vd + idxA.w, dbA);
    atomicMax(vd + idxB.x, dbB);
    atomicMax(vd + idxB.y, dbB);
    atomicMax(vd + idxB.z, dbB);
    atomicMax(vd + idxB.w, dbB);
}

extern "C" void kernel_launch(void* const* d_in, const int* in_sizes, int n_in,
                              void* d_out, int out_size, void* d_ws, size_t ws_size,
                              hipStream_t stream) {
    const float* verts   = (const float*)d_in[0];
    const int*   indices = (const int*)d_in[1];
    const float* density = (const float*)d_in[2];
    int T = in_sizes[2];        // 4,000,000 tets
    int V = in_sizes[0] / 3;    // 1,000,000 vertices

    float* out       = (float*)d_out;
    float* out_area  = out;
    float* out_alpha = out + (size_t)T;
    unsigned int* vd = (unsigned int*)(out + 2 * (size_t)T);

    const int block = 256;
    int H = T >> 1;
    int grid_t = (H + block - 1) / block;

    size_t copies_bytes = (size_t)NUM_XCD * V * sizeof(unsigned int); // 32 MB
    size_t packed_bytes = (size_t)V * sizeof(float4);                 // 16 MB

    if (ws_size >= copies_bytes + packed_bytes) {
        unsigned int* vd_copies = (unsigned int*)d_ws;
        float4* packed = (float4*)((char*)d_ws + copies_bytes);

        // zero the per-XCD copies (ws is poisoned 0xAA each call; 0 = max identity)
        hipMemsetAsync(vd_copies, 0, copies_bytes, stream);

        int grid_r = (V + block - 1) / block;
        repack_kernel<<<grid_r, block, 0, stream>>>(verts, packed, V);

        tet_kernel_fast<<<grid_t, block, 0, stream>>>(packed, indices, density,
                                                      out_area, out_alpha,
                                                      vd_copies, T, V);

        int n4 = V / 4;
        int grid_v = (n4 + block - 1) / block;
        reduce_vd_kernel<<<grid_v, block, 0, stream>>>((const uint4*)vd_copies,
                                                       (uint4*)vd, n4, V);
    } else {
        int n4 = V / 4;
        int grid_z = (n4 + block - 1) / block;
        zero_vd_kernel<<<grid_z, block, 0, stream>>>((float4*)vd, n4);
        tet_kernel_fb<<<grid_t, block, 0, stream>>>(verts, indices, density,
                                                    out_area, out_alpha, vd, T);
    }
}